// Round 4
// baseline (677.772 us; speedup 1.0000x reference)
//
#include <hip/hip_runtime.h>
#include <hip/hip_bf16.h>

typedef __hip_bfloat16 bf16;

// Problem constants
constexpr int Nn  = 4;
constexpr int Ci  = 256;
constexpr int Cc  = 64;
constexpr int Hh  = 128;
constexpr int Ww  = 128;
constexpr int HWh = Hh * Ww;
constexpr int Hl  = 64;
constexpr int Wl  = 64;
constexpr int HWl = Hl * Wl;
constexpr int K2L = 25;
constexpr int K2H = 9;

// Output element offsets (in output elements): [mask | hr_out | lr_out]
constexpr size_t OFF_MASK = 0;
constexpr size_t OFF_HR   = (size_t)Nn * K2L * HWh;            // 1,638,400
constexpr size_t OFF_LR   = OFF_HR + (size_t)Nn * Ci * HWh;    // 18,415,616

// Arena A (inside out_lr region; min capacity 8,388,608 f32 in bf16 mode)
constexpr size_t A_CHF    = 0;        // 4,194,304  [D2-D4]
constexpr size_t A_MLRHR  = 0;        // 1,638,400  [D5-D6]  (chf dead)
constexpr size_t A_MLRLL  = 4300000;  //   409,600  [D3-D6]
constexpr size_t A_CLFE2  = 4800000;  //   147,456  [D3-D7]
constexpr size_t A_MHRRAW = 5000000;  //   589,824  [D7-D8] raw mask_hr
constexpr size_t A_WHR    = 7800000;  // 16,384 weights, live D1-D5
constexpr size_t A_WLR    = 7820000;  // 16,384
constexpr size_t A_WENC   = 7840000;  // 14,400
constexpr size_t A_WENC2  = 7860000;  //  5,184
constexpr size_t A_BHR    = 7870000;  // 64
constexpr size_t A_BLR    = 7870100;  // 64
constexpr size_t A_BENC   = 7870200;  // 64
constexpr size_t A_BENC2  = 7870300;  // 64   -> top 7,870,364 < 8,388,608 OK

// Arena B (inside out_hr region)
constexpr size_t B_CLF    = 0;        // 1,048,576  [D2-D3]
constexpr size_t B_CHF2   = 1100000;  // 4,194,304  [D4-D5]
constexpr size_t B_MHRHR  = 5300000;  //   589,824  [D3-D7]  -> top 5,889,824 OK
constexpr size_t B_MLR    = 0;        // 1,638,400  [D6-D7]

__device__ __forceinline__ float tofloat(float v) { return v; }
__device__ __forceinline__ float tofloat(bf16 v) { return __bfloat162float(v); }

template<typename T> __device__ __forceinline__ T fromfloat(float v);
template<> __device__ __forceinline__ float fromfloat<float>(float v) { return v; }
template<> __device__ __forceinline__ bf16  fromfloat<bf16>(float v)  { return __float2bfloat16(v); }

// f32 scratch pointer inside an output region whose byte address depends on
// the detected output dtype (region offsets are in OUTPUT elements).
__device__ __forceinline__ float* scrp(void* d, int f32, size_t reg, size_t off) {
  float* b = f32 ? ((float*)d + reg) : (float*)((bf16*)d + reg);
  return b + off;
}

// ---------------------------------------------------------------------------
// dtype detector: bf16 data -> all sane values; f32 data read as bf16 ->
// ~half the half-words are |v|>1000 or NaN. flag=1 means f32 mode.
// ---------------------------------------------------------------------------
__global__ void detect_dtype(const void* feat, int* flag) {
  __shared__ int s;
  if (threadIdx.x == 0) s = 0;
  __syncthreads();
  unsigned short b = ((const unsigned short*)feat)[threadIdx.x];
  float v = __uint_as_float(((unsigned int)b) << 16);
  if (!(fabsf(v) < 1000.0f)) atomicOr(&s, 1);
  __syncthreads();
  if (threadIdx.x == 0) *flag = s;
}

// ---------------------------------------------------------------------------
// Weight prep (dtype-dual)
// ---------------------------------------------------------------------------
template<typename T>
__device__ void prep_body(const T* hw, const T* hb, const T* lw, const T* lb,
                          const T* ew, const T* eb, const T* e2w, const T* e2b,
                          float* whr, float* wlr, float* wenc, float* wenc2,
                          float* bhr, float* blr, float* benc, float* benc2) {
  int tid = blockIdx.x * 256 + threadIdx.x, nt = gridDim.x * 256;
  for (int i = tid; i < Cc * Ci; i += nt) {
    int co = i / Ci, ci = i % Ci;
    whr[ci * Cc + co] = tofloat(hw[i]);
    wlr[ci * Cc + co] = tofloat(lw[i]);
  }
  for (int i = tid; i < K2L * Cc * 9; i += nt) {
    int ko = i / (Cc * 9), r = i % (Cc * 9), ci = r / 9, k = r % 9;
    wenc[(ci * K2L + ko) * 9 + k] = tofloat(ew[i]);
  }
  for (int i = tid; i < K2H * Cc * 9; i += nt) {
    int ko = i / (Cc * 9), r = i % (Cc * 9), ci = r / 9, k = r % 9;
    wenc2[(ci * K2H + ko) * 9 + k] = tofloat(e2w[i]);
  }
  if (tid < Cc)  { bhr[tid] = tofloat(hb[tid]); blr[tid] = tofloat(lb[tid]); }
  if (tid < K2L) benc[tid]  = tofloat(eb[tid]);
  if (tid < K2H) benc2[tid] = tofloat(e2b[tid]);
}

__global__ void prep_weights(const int* flag, void* dout,
                             const void* hw, const void* hb, const void* lw, const void* lb,
                             const void* ew, const void* eb, const void* e2w, const void* e2b) {
  int f32 = *flag;
  float* whr   = scrp(dout, f32, OFF_LR, A_WHR);
  float* wlr   = scrp(dout, f32, OFF_LR, A_WLR);
  float* wenc  = scrp(dout, f32, OFF_LR, A_WENC);
  float* wenc2 = scrp(dout, f32, OFF_LR, A_WENC2);
  float* bhr   = scrp(dout, f32, OFF_LR, A_BHR);
  float* blr   = scrp(dout, f32, OFF_LR, A_BLR);
  float* benc  = scrp(dout, f32, OFF_LR, A_BENC);
  float* benc2 = scrp(dout, f32, OFF_LR, A_BENC2);
  if (f32) prep_body<float>((const float*)hw, (const float*)hb, (const float*)lw, (const float*)lb,
                            (const float*)ew, (const float*)eb, (const float*)e2w, (const float*)e2b,
                            whr, wlr, wenc, wenc2, bhr, blr, benc, benc2);
  else     prep_body<bf16>((const bf16*)hw, (const bf16*)hb, (const bf16*)lw, (const bf16*)lb,
                           (const bf16*)ew, (const bf16*)eb, (const bf16*)e2w, (const bf16*)e2b,
                           whr, wlr, wenc, wenc2, bhr, blr, benc, benc2);
}

// ---------------------------------------------------------------------------
// 1x1 conv core (dtype-dual input, f32 scratch output)
// ---------------------------------------------------------------------------
template<typename T, int CW>
__device__ __forceinline__ void conv1x1_core(const T* __restrict__ in, const float* __restrict__ wt,
                                             const float* __restrict__ bias, float* __restrict__ out,
                                             int P, int n, int pbase, int co0) {
  const T* inp = in + (size_t)n * Ci * P + pbase;
  float acc[CW];
  #pragma unroll
  for (int c = 0; c < CW; ++c) acc[c] = bias[co0 + c];

  #pragma unroll 4
  for (int ci = 0; ci < Ci; ++ci) {
    float v = tofloat(inp[(size_t)ci * P]);
    const float* wr = wt + ci * Cc + co0;
    #pragma unroll
    for (int c = 0; c < CW; ++c) acc[c] = fmaf(v, wr[c], acc[c]);
  }
  float* op = out + (size_t)n * Cc * P + pbase;
  #pragma unroll
  for (int c = 0; c < CW; ++c) op[(size_t)(co0 + c) * P] = acc[c];
}

// D2: both 1x1 convs in one launch. HR: 1024 blocks (CW=16). LR: 512 (CW=8).
__global__ __launch_bounds__(256) void conv1x1_both_k(const int* flag, void* dout,
                                                      const void* hr, const void* lr) {
  const int f32 = __builtin_amdgcn_readfirstlane(*flag);
  const float* whr = scrp(dout, f32, OFF_LR, A_WHR);
  const float* wlr = scrp(dout, f32, OFF_LR, A_WLR);
  const float* bhr = scrp(dout, f32, OFF_LR, A_BHR);
  const float* blr = scrp(dout, f32, OFF_LR, A_BLR);
  float* ochf = scrp(dout, f32, OFF_LR, A_CHF);
  float* oclf = scrp(dout, f32, OFF_HR, B_CLF);
  const int tid = threadIdx.x;
  int b = blockIdx.x;
  if (b < Nn * 256) {
    const int n = b >> 8, xb = b & 255;
    const int pbase = xb * 64 + (tid & 63);
    const int co0 = __builtin_amdgcn_readfirstlane((tid >> 6) * 16);
    if (f32) conv1x1_core<float, 16>((const float*)hr, whr, bhr, ochf, HWh, n, pbase, co0);
    else     conv1x1_core<bf16, 16>((const bf16*)hr, whr, bhr, ochf, HWh, n, pbase, co0);
  } else {
    b -= Nn * 256;
    const int n = b >> 7, rem = b & 127;
    const int pbase = (rem & 63) * 64 + (tid & 63);
    const int co0 = __builtin_amdgcn_readfirstlane((rem >> 6) * 32 + (tid >> 6) * 8);
    if (f32) conv1x1_core<float, 8>((const float*)lr, wlr, blr, oclf, HWl, n, pbase, co0);
    else     conv1x1_core<bf16, 8>((const bf16*)lr, wlr, blr, oclf, HWl, n, pbase, co0);
  }
}

// ---------------------------------------------------------------------------
// 3x3 conv body, pad=1 (f32 scratch in/out); computes KOG of KO channels.
// Interior blocks skip all bounds checks in staging.
// ---------------------------------------------------------------------------
template<int KO, int KOG>
__device__ __forceinline__ void conv3x3_body(const float* __restrict__ in,
                                             const float* __restrict__ wt,
                                             const float* __restrict__ bias,
                                             float* __restrict__ out,
                                             int hh, int ww, int n, int ko0,
                                             int bx, int by, float* tile) {
  const int tid = threadIdx.x;
  const int tx = tid & 15, ty = tid >> 4;
  const bool inter = (bx >= 16) && (by >= 16) && (bx + 32 <= ww) && (by + 32 <= hh);

  float acc[KOG];
  #pragma unroll
  for (int ko = 0; ko < KOG; ++ko) acc[ko] = bias[ko0 + ko];

  for (int cc = 0; cc < Cc; cc += 16) {
    __syncthreads();
    if (inter) {
      for (int i = tid; i < 16 * 324; i += 256) {
        int ci = i / 324, r = i % 324, yy = r / 18, xx = r % 18;
        tile[i] = in[(((size_t)n * Cc + cc + ci) * hh + by + yy - 1) * ww + bx + xx - 1];
      }
    } else {
      for (int i = tid; i < 16 * 324; i += 256) {
        int ci = i / 324, r = i % 324, yy = r / 18, xx = r % 18;
        int gy = by + yy - 1, gx = bx + xx - 1;
        float v = 0.f;
        if (gy >= 0 && gy < hh && gx >= 0 && gx < ww)
          v = in[(((size_t)n * Cc + cc + ci) * hh + gy) * ww + gx];
        tile[i] = v;
      }
    }
    __syncthreads();
    for (int ci = 0; ci < 16; ++ci) {
      float nb[9];
      #pragma unroll
      for (int dy = 0; dy < 3; ++dy)
        #pragma unroll
        for (int dx = 0; dx < 3; ++dx)
          nb[dy * 3 + dx] = tile[ci * 324 + (ty + dy) * 18 + tx + dx];
      const float* wr = wt + ((size_t)(cc + ci) * KO + ko0) * 9;
      #pragma unroll
      for (int ko = 0; ko < KOG; ++ko)
        #pragma unroll
        for (int k = 0; k < 9; ++k)
          acc[ko] = fmaf(wr[ko * 9 + k], nb[k], acc[ko]);
    }
  }
  const size_t ob = (((size_t)n * KO + ko0) * hh + by + ty) * ww + bx + tx;
  #pragma unroll
  for (int ko = 0; ko < KOG; ++ko) out[ob + (size_t)ko * hh * ww] = acc[ko];
}

// D5: conv3x3<25,5>(chf2) @128, 3D grid.
template<int KO, int KOG>
__global__ __launch_bounds__(256) void conv3x3_k(const int* flag, void* dout,
                                                 size_t i_reg, size_t i_off,
                                                 size_t w_off, size_t b_off,
                                                 size_t o_reg, size_t o_off, int hh, int ww) {
  const int f32 = __builtin_amdgcn_readfirstlane(*flag);
  const float* in   = scrp(dout, f32, i_reg, i_off);
  const float* wt   = scrp(dout, f32, OFF_LR, w_off);
  const float* bias = scrp(dout, f32, OFF_LR, b_off);
  float* out        = scrp(dout, f32, o_reg, o_off);

  constexpr int NG = KO / KOG;
  __shared__ float tile[16 * 324];
  const int n = blockIdx.z / NG;
  const int ko0 = (blockIdx.z % NG) * KOG;
  conv3x3_body<KO, KOG>(in, wt, bias, out, hh, ww, n, ko0, blockIdx.x * 16, blockIdx.y * 16, tile);
}

// D3: conv3x3<9,3>(chf)@128 (768 blocks) + dual clf convs @64 (512 blocks), one launch.
__global__ __launch_bounds__(256) void fused_s3_k(const int* flag, void* dout) {
  const int f32 = __builtin_amdgcn_readfirstlane(*flag);
  const float* chf   = scrp(dout, f32, OFF_LR, A_CHF);
  const float* clf   = scrp(dout, f32, OFF_HR, B_CLF);
  const float* wenc  = scrp(dout, f32, OFF_LR, A_WENC);
  const float* benc  = scrp(dout, f32, OFF_LR, A_BENC);
  const float* wenc2 = scrp(dout, f32, OFF_LR, A_WENC2);
  const float* benc2 = scrp(dout, f32, OFF_LR, A_BENC2);
  float* o_mhrhr = scrp(dout, f32, OFF_HR, B_MHRHR);
  float* o_ll    = scrp(dout, f32, OFF_LR, A_MLRLL);
  float* o_e2    = scrp(dout, f32, OFF_LR, A_CLFE2);
  __shared__ float tile[16 * 324];
  int b = blockIdx.x;
  if (b < Nn * 3 * 64) {
    const int z = b >> 6, rem = b & 63;
    conv3x3_body<K2H, 3>(chf, wenc2, benc2, o_mhrhr, Hh, Ww, z / 3, (z % 3) * 3,
                         (rem & 7) * 16, (rem >> 3) * 16, tile);
  } else {
    b -= Nn * 3 * 64;
    const int z = b >> 4, rem = b & 15;
    const int bx = (rem & 3) * 16, by = (rem >> 2) * 16;
    const int g = z & 7, n = z >> 3;
    if (g < 5) conv3x3_body<K2L, 5>(clf, wenc, benc, o_ll, Hl, Wl, n, g * 5, bx, by, tile);
    else       conv3x3_body<K2H, 3>(clf, wenc2, benc2, o_e2, Hl, Wl, n, (g - 5) * 3, bx, by, tile);
  }
}

// ---------------------------------------------------------------------------
// s=1 CARAFE fused residual: out = 2*feat - sum_{3x3} feat_pad * softmax?(mask)
// Interior blocks skip stencil bounds checks.
// ---------------------------------------------------------------------------
template<typename FT, typename OT, int FINAL, int SM>
__device__ void carafe1_body(const FT* __restrict__ feat, const float* __restrict__ mask,
                             void* dout, size_t out_reg, float* outscr, int C, int CPB) {
  const int tid = threadIdx.x;
  const int tx = tid & 15, ty = tid >> 4;
  const int bx = blockIdx.x * 16, by = blockIdx.y * 16;
  const int numCG = C / CPB;
  const int n = blockIdx.z / numCG, cg = blockIdx.z % numCG;
  const int x = bx + tx, y = by + ty;
  const bool inter = (bx >= 16) && (by >= 16) && (bx + 32 <= Ww) && (by + 32 <= Hh);

  float mv[9];
  #pragma unroll
  for (int k = 0; k < 9; ++k)
    mv[k] = mask[(((size_t)n * 9 + k) * Hh + y) * Ww + x];
  if (SM) {
    float m = -1e30f;
    #pragma unroll
    for (int k = 0; k < 9; ++k) m = fmaxf(m, mv[k]);
    float s = 0.f;
    #pragma unroll
    for (int k = 0; k < 9; ++k) { mv[k] = __expf(mv[k] - m); s += mv[k]; }
    const float inv = 1.0f / s;
    #pragma unroll
    for (int k = 0; k < 9; ++k) mv[k] *= inv;
  }

  const int c0 = cg * CPB;
  if (inter) {
    for (int c = c0; c < c0 + CPB; ++c) {
      const FT* fp = feat + ((size_t)n * C + c) * HWh + (size_t)y * Ww + x;
      float center = tofloat(fp[0]);
      float s = 0.f;
      #pragma unroll
      for (int dy = -1; dy <= 1; ++dy)
        #pragma unroll
        for (int dx = -1; dx <= 1; ++dx)
          s = fmaf(tofloat(fp[dy * Ww + dx]), mv[(dy + 1) * 3 + (dx + 1)], s);
      float r = 2.f * center - s;
      const size_t li = ((size_t)n * C + c) * HWh + (size_t)y * Ww + x;
      if (FINAL) ((OT*)dout)[out_reg + li] = fromfloat<OT>(r);
      else       outscr[li] = r;
    }
  } else {
    for (int c = c0; c < c0 + CPB; ++c) {
      const FT* fp = feat + ((size_t)n * C + c) * HWh;
      float s = 0.f, center = 0.f;
      #pragma unroll
      for (int dy = -1; dy <= 1; ++dy)
        #pragma unroll
        for (int dx = -1; dx <= 1; ++dx) {
          int yy = y + dy, xx = x + dx;
          float fv = 0.f;
          if (yy >= 0 && yy < Hh && xx >= 0 && xx < Ww) fv = tofloat(fp[yy * Ww + xx]);
          if (dy == 0 && dx == 0) center = fv;
          s = fmaf(fv, mv[(dy + 1) * 3 + (dx + 1)], s);
        }
      float r = 2.f * center - s;
      const size_t li = ((size_t)n * C + c) * HWh + (size_t)y * Ww + x;
      if (FINAL) ((OT*)dout)[out_reg + li] = fromfloat<OT>(r);
      else       outscr[li] = r;
    }
  }
}

// D4: feat/mask f32 scratch, softmax fused, out scratch
__global__ __launch_bounds__(256) void carafe1_scr_k(const int* flag, void* dout,
    size_t f_reg, size_t f_off, size_t m_reg, size_t m_off, size_t o_reg, size_t o_off,
    int C, int CPB) {
  int f32 = __builtin_amdgcn_readfirstlane(*flag);
  carafe1_body<float, float, 0, 1>(scrp(dout, f32, f_reg, f_off), scrp(dout, f32, m_reg, m_off),
                                   dout, 0, scrp(dout, f32, o_reg, o_off), C, CPB);
}

// D8: feat = input hr_feat, mask raw f32 scratch (softmax fused), out final
__global__ __launch_bounds__(256) void carafe1_io_k(const int* flag, void* dout, const void* feat,
    size_t m_reg, size_t m_off, size_t out_reg, int C, int CPB) {
  int f32 = __builtin_amdgcn_readfirstlane(*flag);
  const float* m = scrp(dout, f32, m_reg, m_off);
  if (f32) carafe1_body<float, float, 1, 1>((const float*)feat, m, dout, out_reg, nullptr, C, CPB);
  else     carafe1_body<bf16, bf16, 1, 1>((const bf16*)feat, m, dout, out_reg, nullptr, C, CPB);
}

// ---------------------------------------------------------------------------
// s=2 CARAFE upsample (k=5): feat 64x64 -> out 128x128
// SM=1 softmaxes in-register; WMASK=1 additionally writes the softmaxed mask
// to final output 0 (dtype MOT) from cg==0 blocks. Interior staging fast path.
// ---------------------------------------------------------------------------
template<typename FT, typename MT, typename OT, typename MOT, int ADD, int FINAL, int SM, int WMASK>
__device__ void carafe2_body(const FT* __restrict__ feat, const MT* __restrict__ mask,
                             const float* __restrict__ addend, void* dout, size_t out_reg,
                             float* outscr, int C, int CPB) {
  __shared__ float ft[8][144];
  const int tid = threadIdx.x;
  const int tx = tid & 15, ty = tid >> 4;
  const int bx = blockIdx.x * 16, by = blockIdx.y * 16;
  const int numCG = C / CPB;
  const int n = blockIdx.z / numCG, cg = blockIdx.z % numCG;
  const int x = bx + tx, y = by + ty;
  const bool inter = (bx >= 16) && (by >= 16) && (bx + 32 <= Ww) && (by + 32 <= Hh);

  float mv[25];
  #pragma unroll
  for (int k = 0; k < 25; ++k)
    mv[k] = tofloat(mask[(((size_t)n * 25 + k) * Hh + y) * Ww + x]);
  if (SM) {
    float m = -1e30f;
    #pragma unroll
    for (int k = 0; k < 25; ++k) m = fmaxf(m, mv[k]);
    float s = 0.f;
    #pragma unroll
    for (int k = 0; k < 25; ++k) { mv[k] = __expf(mv[k] - m); s += mv[k]; }
    const float inv = 1.0f / s;
    #pragma unroll
    for (int k = 0; k < 25; ++k) mv[k] *= inv;
  }
  if (WMASK && cg == 0) {
    const size_t g = (size_t)n * 25 * HWh + (size_t)y * Ww + x;
    MOT* mo = (MOT*)dout;
    #pragma unroll
    for (int k = 0; k < 25; ++k) mo[g + (size_t)k * HWh] = fromfloat<MOT>(mv[k]);
  }

  const int fy0 = (by >> 1) - 2, fx0 = (bx >> 1) - 2;
  const int fyb = (ty >> 1) + 2, fxb = (tx >> 1) + 2;
  const int c0 = cg * CPB;

  for (int cb = 0; cb < CPB; cb += 8) {
    const int lim = (CPB - cb < 8) ? (CPB - cb) : 8;
    __syncthreads();
    if (inter) {
      for (int i = tid; i < lim * 144; i += 256) {
        int cc = i / 144, r = i % 144, fy = r / 12, fx = r % 12;
        ft[cc][r] = tofloat(feat[((size_t)n * C + c0 + cb + cc) * HWl + (fy0 + fy) * Wl + fx0 + fx]);
      }
    } else {
      for (int i = tid; i < lim * 144; i += 256) {
        int cc = i / 144, r = i % 144, fy = r / 12, fx = r % 12;
        int gy = fy0 + fy, gx = fx0 + fx;
        float v = 0.f;
        if (gy >= 0 && gy < Hl && gx >= 0 && gx < Wl)
          v = tofloat(feat[((size_t)n * C + c0 + cb + cc) * HWl + gy * Wl + gx]);
        ft[cc][r] = v;
      }
    }
    __syncthreads();
    for (int cc = 0; cc < lim; ++cc) {
      float s = 0.f;
      #pragma unroll
      for (int ki = 0; ki < 5; ++ki)
        #pragma unroll
        for (int kj = 0; kj < 5; ++kj)
          s = fmaf(ft[cc][(fyb + ki - 2) * 12 + (fxb + kj - 2)], mv[ki * 5 + kj], s);
      const size_t li = (((size_t)n * C + c0 + cb + cc) * Hh + y) * Ww + x;
      float r = ADD ? (addend[li] + s) : s;
      if (FINAL) ((OT*)dout)[out_reg + li] = fromfloat<OT>(r);
      else       outscr[li] = r;
    }
  }
}

// D6: all f32 scratch, mask raw (softmax fused), ADD
__global__ __launch_bounds__(256) void carafe2_scr_k(const int* flag, void* dout,
    size_t f_reg, size_t f_off, size_t m_reg, size_t m_off, size_t a_reg, size_t a_off,
    size_t o_reg, size_t o_off, int C, int CPB) {
  int f32 = __builtin_amdgcn_readfirstlane(*flag);
  carafe2_body<float, float, float, float, 1, 0, 1, 0>(
      scrp(dout, f32, f_reg, f_off), scrp(dout, f32, m_reg, m_off),
      scrp(dout, f32, a_reg, a_off), dout, 0, scrp(dout, f32, o_reg, o_off), C, CPB);
}

// D7: mask_hr = mask_hr_hr + carafe_s2(clf_e2, softmax(mask_lr raw)); ALSO
// writes softmax(mask_lr) to final output 0 (replaces the softmax dispatch).
__global__ __launch_bounds__(256) void carafe2_m0_k(const int* flag, void* dout,
    size_t f_reg, size_t f_off, size_t m_reg, size_t m_off, size_t a_reg, size_t a_off,
    size_t o_reg, size_t o_off, int C, int CPB) {
  int f32 = __builtin_amdgcn_readfirstlane(*flag);
  const float* f = scrp(dout, f32, f_reg, f_off);
  const float* m = scrp(dout, f32, m_reg, m_off);
  const float* a = scrp(dout, f32, a_reg, a_off);
  float* o = scrp(dout, f32, o_reg, o_off);
  if (f32) carafe2_body<float, float, float, float, 1, 0, 1, 1>(f, m, a, dout, 0, o, C, CPB);
  else     carafe2_body<float, float, float, bf16, 1, 0, 1, 1>(f, m, a, dout, 0, o, C, CPB);
}

// D9: feat = input, mask = final output 0 (already softmaxed), out = final out_lr
__global__ __launch_bounds__(256) void carafe2_io_k(const int* flag, void* dout, const void* feat,
    size_t out_reg, int C, int CPB) {
  int f32 = __builtin_amdgcn_readfirstlane(*flag);
  if (f32) carafe2_body<float, float, float, float, 0, 1, 0, 0>((const float*)feat, (const float*)dout,
      nullptr, dout, out_reg, nullptr, C, CPB);
  else     carafe2_body<bf16, bf16, bf16, bf16, 0, 1, 0, 0>((const bf16*)feat, (const bf16*)dout,
      nullptr, dout, out_reg, nullptr, C, CPB);
}

// ---------------------------------------------------------------------------
extern "C" void kernel_launch(void* const* d_in, const int* in_sizes, int n_in,
                              void* d_out, int out_size, void* d_ws, size_t ws_size,
                              hipStream_t stream) {
  const void* hr_feat = d_in[0];
  const void* lr_feat = d_in[1];
  int* flag = (int*)d_ws;  // only 4 bytes of ws used

  // D0. dtype detect
  detect_dtype<<<1, 256, 0, stream>>>(hr_feat, flag);
  // D1. weight prep -> arena A weight slots
  prep_weights<<<64, 256, 0, stream>>>(flag, d_out, d_in[2], d_in[3], d_in[4], d_in[5],
                                       d_in[6], d_in[7], d_in[8], d_in[9]);
  // D2. chf = conv1x1(hr_feat) -> A ; clf = conv1x1(lr_feat) -> B   [one launch, 1536 blocks]
  conv1x1_both_k<<<Nn * 256 + Nn * 128, 256, 0, stream>>>(flag, d_out, hr_feat, lr_feat);
  // D3. mask_hr_hr = conv3x3(chf, enc2) -> B  +  {m_lr_ll, clf_e2} = conv3x3(clf, enc/enc2) -> A
  fused_s3_k<<<Nn * 3 * 64 + Nn * 8 * 16, 256, 0, stream>>>(flag, d_out);
  // D4. chf2 = 2*chf - carafe_s1(chf, softmax(mask_hr_hr)) -> B
  carafe1_scr_k<<<dim3(8, 8, Nn * (Cc / 16)), 256, 0, stream>>>(flag, d_out, OFF_LR, A_CHF, OFF_HR, B_MHRHR, OFF_HR, B_CHF2, Cc, 16);
  // D5. mask_lr_hr = conv3x3(chf2, enc) -> A (chf dead)
  conv3x3_k<K2L, 5><<<dim3(8, 8, Nn * 5), 256, 0, stream>>>(flag, d_out, OFF_HR, B_CHF2, A_WENC, A_BENC, OFF_LR, A_MLRHR, Hh, Ww);
  // D6. mask_lr = mask_lr_hr + carafe_s2(m_lr_ll, softmax(mask_lr_hr)) -> B
  carafe2_scr_k<<<dim3(8, 8, Nn * 5), 256, 0, stream>>>(flag, d_out, OFF_LR, A_MLRLL, OFF_LR, A_MLRHR,
                                                        OFF_LR, A_MLRHR, OFF_HR, B_MLR, K2L, 5);
  // D7. mask_hr(raw) = mask_hr_hr + carafe_s2(clf_e2, softmax(mask_lr)) -> A
  //     + write softmax(mask_lr) -> FINAL output 0
  carafe2_m0_k<<<dim3(8, 8, Nn * 3), 256, 0, stream>>>(flag, d_out, OFF_LR, A_CLFE2,
                                                       OFF_HR, B_MLR, OFF_HR, B_MHRHR,
                                                       OFF_LR, A_MHRRAW, K2H, 3);
  // D8. hr_out = 2*hr_feat - carafe_s1(hr_feat, softmax(mask_hr)) -> FINAL out_hr
  carafe1_io_k<<<dim3(8, 8, Nn * (Ci / 32)), 256, 0, stream>>>(flag, d_out, hr_feat,
                                                               OFF_LR, A_MHRRAW, OFF_HR, Ci, 32);
  // D9 (last). lr_out = carafe_s2(lr_feat, mask_lr_out) -> FINAL out_lr (overwrites arena A)
  carafe2_io_k<<<dim3(8, 8, Nn * (Ci / 32)), 256, 0, stream>>>(flag, d_out, lr_feat, OFF_LR, Ci, 32);
}

// Round 6
// 569.227 us; speedup vs baseline: 1.1907x; 1.1907x over previous
//
#include <hip/hip_runtime.h>
#include <hip/hip_bf16.h>

typedef __hip_bfloat16 bf16;

// Problem constants
constexpr int Nn  = 4;
constexpr int Ci  = 256;
constexpr int Cc  = 64;
constexpr int Hh  = 128;
constexpr int Ww  = 128;
constexpr int HWh = Hh * Ww;
constexpr int Hl  = 64;
constexpr int Wl  = 64;
constexpr int HWl = Hl * Wl;
constexpr int K2L = 25;
constexpr int K2H = 9;

// Output element offsets (in output elements): [mask | hr_out | lr_out]
constexpr size_t OFF_MASK = 0;
constexpr size_t OFF_HR   = (size_t)Nn * K2L * HWh;            // 1,638,400
constexpr size_t OFF_LR   = OFF_HR + (size_t)Nn * Ci * HWh;    // 18,415,616

// Arena A (inside out_lr region; min capacity 8,388,608 f32 in bf16 mode)
constexpr size_t A_CHF    = 0;        // 4,194,304  [D2-D5]
constexpr size_t A_MLRHR  = 0;        // 1,638,400  [D6-D7]  (chf dead)
constexpr size_t A_MLRLL  = 4300000;  //   409,600  [D4-D7]
constexpr size_t A_CLFE2  = 4800000;  //   147,456  [D4-D8]
constexpr size_t A_MHRRAW = 5000000;  //   589,824  [D8-D9] raw mask_hr
constexpr size_t A_WHR    = 7800000;  // 16,384 weights, live D1-D6
constexpr size_t A_WLR    = 7820000;  // 16,384
constexpr size_t A_WENC   = 7840000;  // 14,400
constexpr size_t A_WENC2  = 7860000;  //  5,184
constexpr size_t A_BHR    = 7870000;  // 64
constexpr size_t A_BLR    = 7870100;  // 64
constexpr size_t A_BENC   = 7870200;  // 64
constexpr size_t A_BENC2  = 7870300;  // 64   -> top 7,870,364 < 8,388,608 OK

// Arena B (inside out_hr region)
constexpr size_t B_CLF    = 0;        // 1,048,576  [D2-D4]
constexpr size_t B_CHF2   = 1100000;  // 4,194,304  [D5-D6]
constexpr size_t B_MHRHR  = 5300000;  //   589,824  [D3-D8]  -> top 5,889,824 OK
constexpr size_t B_MLR    = 0;        // 1,638,400  [D7-D8]

__device__ __forceinline__ float tofloat(float v) { return v; }
__device__ __forceinline__ float tofloat(bf16 v) { return __bfloat162float(v); }

template<typename T> __device__ __forceinline__ T fromfloat(float v);
template<> __device__ __forceinline__ float fromfloat<float>(float v) { return v; }
template<> __device__ __forceinline__ bf16  fromfloat<bf16>(float v)  { return __float2bfloat16(v); }

// f32 scratch pointer inside an output region whose byte address depends on
// the detected output dtype (region offsets are in OUTPUT elements).
__device__ __forceinline__ float* scrp(void* d, int f32, size_t reg, size_t off) {
  float* b = f32 ? ((float*)d + reg) : (float*)((bf16*)d + reg);
  return b + off;
}

// ---------------------------------------------------------------------------
// dtype detector
// ---------------------------------------------------------------------------
__global__ void detect_dtype(const void* feat, int* flag) {
  __shared__ int s;
  if (threadIdx.x == 0) s = 0;
  __syncthreads();
  unsigned short b = ((const unsigned short*)feat)[threadIdx.x];
  float v = __uint_as_float(((unsigned int)b) << 16);
  if (!(fabsf(v) < 1000.0f)) atomicOr(&s, 1);
  __syncthreads();
  if (threadIdx.x == 0) *flag = s;
}

// ---------------------------------------------------------------------------
// Weight prep (dtype-dual)
// ---------------------------------------------------------------------------
template<typename T>
__device__ void prep_body(const T* hw, const T* hb, const T* lw, const T* lb,
                          const T* ew, const T* eb, const T* e2w, const T* e2b,
                          float* whr, float* wlr, float* wenc, float* wenc2,
                          float* bhr, float* blr, float* benc, float* benc2) {
  int tid = blockIdx.x * 256 + threadIdx.x, nt = gridDim.x * 256;
  for (int i = tid; i < Cc * Ci; i += nt) {
    int co = i / Ci, ci = i % Ci;
    whr[ci * Cc + co] = tofloat(hw[i]);
    wlr[ci * Cc + co] = tofloat(lw[i]);
  }
  for (int i = tid; i < K2L * Cc * 9; i += nt) {
    int ko = i / (Cc * 9), r = i % (Cc * 9), ci = r / 9, k = r % 9;
    wenc[(ci * K2L + ko) * 9 + k] = tofloat(ew[i]);
  }
  for (int i = tid; i < K2H * Cc * 9; i += nt) {
    int ko = i / (Cc * 9), r = i % (Cc * 9), ci = r / 9, k = r % 9;
    wenc2[(ci * K2H + ko) * 9 + k] = tofloat(e2w[i]);
  }
  if (tid < Cc)  { bhr[tid] = tofloat(hb[tid]); blr[tid] = tofloat(lb[tid]); }
  if (tid < K2L) benc[tid]  = tofloat(eb[tid]);
  if (tid < K2H) benc2[tid] = tofloat(e2b[tid]);
}

__global__ void prep_weights(const int* flag, void* dout,
                             const void* hw, const void* hb, const void* lw, const void* lb,
                             const void* ew, const void* eb, const void* e2w, const void* e2b) {
  int f32 = *flag;
  float* whr   = scrp(dout, f32, OFF_LR, A_WHR);
  float* wlr   = scrp(dout, f32, OFF_LR, A_WLR);
  float* wenc  = scrp(dout, f32, OFF_LR, A_WENC);
  float* wenc2 = scrp(dout, f32, OFF_LR, A_WENC2);
  float* bhr   = scrp(dout, f32, OFF_LR, A_BHR);
  float* blr   = scrp(dout, f32, OFF_LR, A_BLR);
  float* benc  = scrp(dout, f32, OFF_LR, A_BENC);
  float* benc2 = scrp(dout, f32, OFF_LR, A_BENC2);
  if (f32) prep_body<float>((const float*)hw, (const float*)hb, (const float*)lw, (const float*)lb,
                            (const float*)ew, (const float*)eb, (const float*)e2w, (const float*)e2b,
                            whr, wlr, wenc, wenc2, bhr, blr, benc, benc2);
  else     prep_body<bf16>((const bf16*)hw, (const bf16*)hb, (const bf16*)lw, (const bf16*)lb,
                           (const bf16*)ew, (const bf16*)eb, (const bf16*)e2w, (const bf16*)e2b,
                           whr, wlr, wenc, wenc2, bhr, blr, benc, benc2);
}

// ---------------------------------------------------------------------------
// 1x1 conv: 2 pixels/thread (pbase, pbase+64) -> 8 loads in flight with
// unroll 4. Block covers 128 pixels x 4*CW channels.
// ---------------------------------------------------------------------------
template<typename T, int CW>
__device__ __forceinline__ void conv1x1_core(const T* __restrict__ in, const float* __restrict__ wt,
                                             const float* __restrict__ bias, float* __restrict__ out,
                                             int P, int n, int pbase, int co0) {
  const T* inp = in + (size_t)n * Ci * P + pbase;
  float acc0[CW], acc1[CW];
  #pragma unroll
  for (int c = 0; c < CW; ++c) { float b = bias[co0 + c]; acc0[c] = b; acc1[c] = b; }

  #pragma unroll 4
  for (int ci = 0; ci < Ci; ++ci) {
    float v0 = tofloat(inp[(size_t)ci * P]);
    float v1 = tofloat(inp[(size_t)ci * P + 64]);
    const float* wr = wt + ci * Cc + co0;
    #pragma unroll
    for (int c = 0; c < CW; ++c) {
      float wv = wr[c];
      acc0[c] = fmaf(v0, wv, acc0[c]);
      acc1[c] = fmaf(v1, wv, acc1[c]);
    }
  }
  float* op = out + (size_t)n * Cc * P + pbase;
  #pragma unroll
  for (int c = 0; c < CW; ++c) {
    op[(size_t)(co0 + c) * P]      = acc0[c];
    op[(size_t)(co0 + c) * P + 64] = acc1[c];
  }
}

template<int CW>
__global__ __launch_bounds__(256) void conv1x1_k(const int* flag, void* dout, const void* in,
                                                 size_t w_off, size_t b_off,
                                                 size_t o_reg, size_t o_off, int P) {
  int f32 = __builtin_amdgcn_readfirstlane(*flag);
  const float* wt   = scrp(dout, f32, OFF_LR, w_off);
  const float* bias = scrp(dout, f32, OFF_LR, b_off);
  float* out        = scrp(dout, f32, o_reg, o_off);
  const int tid = threadIdx.x;
  const int n = blockIdx.z;
  const int pbase = blockIdx.x * 128 + (tid & 63);
  const int co0 = __builtin_amdgcn_readfirstlane(blockIdx.y * 4 * CW + (tid >> 6) * CW);
  if (f32) conv1x1_core<float, CW>((const float*)in, wt, bias, out, P, n, pbase, co0);
  else     conv1x1_core<bf16, CW>((const bf16*)in, wt, bias, out, P, n, pbase, co0);
}

// ---------------------------------------------------------------------------
// 3x3 conv body, pad=1 (f32 scratch in/out); computes KOG of KO channels.
// Register-staged prefetch: next chunk's global loads are issued BEFORE the
// current chunk's compute, hiding HBM/L2 latency under the FMA block.
// ---------------------------------------------------------------------------
constexpr int STG_TOT = 16 * 324;        // 5184 floats per chunk
constexpr int NSTG    = 21;              // ceil(5184/256) regs per thread

template<int KO, int KOG>
__device__ __forceinline__ void conv3x3_body(const float* __restrict__ in,
                                             const float* __restrict__ wt,
                                             const float* __restrict__ bias,
                                             float* __restrict__ out,
                                             int hh, int ww, int n, int ko0,
                                             int bx, int by, float* tile) {
  const int tid = threadIdx.x;
  const int tx = tid & 15, ty = tid >> 4;
  const bool inter = (bx >= 16) && (by >= 16) && (bx + 32 <= ww) && (by + 32 <= hh);

  float acc[KOG];
  #pragma unroll
  for (int ko = 0; ko < KOG; ++ko) acc[ko] = bias[ko0 + ko];

  float rg[NSTG];
  // prologue: load chunk cc=0 into registers
  #pragma unroll
  for (int j = 0; j < NSTG; ++j) {
    int i = tid + j * 256;
    if (i < STG_TOT) {
      int ci = i / 324, r = i % 324, yy = r / 18, xx = r % 18;
      int gy = by + yy - 1, gx = bx + xx - 1;
      float v = 0.f;
      if (inter || (gy >= 0 && gy < hh && gx >= 0 && gx < ww))
        v = in[(((size_t)n * Cc + ci) * hh + gy) * ww + gx];
      rg[j] = v;
    }
  }

  for (int cc = 0; cc < Cc; cc += 16) {
    __syncthreads();
    #pragma unroll
    for (int j = 0; j < NSTG; ++j) {
      int i = tid + j * 256;
      if (i < STG_TOT) tile[i] = rg[j];
    }
    __syncthreads();
    if (cc + 16 < Cc) {
      // issue next chunk's loads now; they complete under the compute below
      #pragma unroll
      for (int j = 0; j < NSTG; ++j) {
        int i = tid + j * 256;
        if (i < STG_TOT) {
          int ci = i / 324, r = i % 324, yy = r / 18, xx = r % 18;
          int gy = by + yy - 1, gx = bx + xx - 1;
          float v = 0.f;
          if (inter || (gy >= 0 && gy < hh && gx >= 0 && gx < ww))
            v = in[(((size_t)n * Cc + cc + 16 + ci) * hh + gy) * ww + gx];
          rg[j] = v;
        }
      }
    }
    for (int ci = 0; ci < 16; ++ci) {
      float nb[9];
      #pragma unroll
      for (int dy = 0; dy < 3; ++dy)
        #pragma unroll
        for (int dx = 0; dx < 3; ++dx)
          nb[dy * 3 + dx] = tile[ci * 324 + (ty + dy) * 18 + tx + dx];
      const float* wr = wt + ((size_t)(cc + ci) * KO + ko0) * 9;
      #pragma unroll
      for (int ko = 0; ko < KOG; ++ko)
        #pragma unroll
        for (int k = 0; k < 9; ++k)
          acc[ko] = fmaf(wr[ko * 9 + k], nb[k], acc[ko]);
    }
  }
  const size_t ob = (((size_t)n * KO + ko0) * hh + by + ty) * ww + bx + tx;
  #pragma unroll
  for (int ko = 0; ko < KOG; ++ko) out[ob + (size_t)ko * hh * ww] = acc[ko];
}

template<int KO, int KOG>
__global__ __launch_bounds__(256) void conv3x3_k(const int* flag, void* dout,
                                                 size_t i_reg, size_t i_off,
                                                 size_t w_off, size_t b_off,
                                                 size_t o_reg, size_t o_off, int hh, int ww) {
  const int f32 = __builtin_amdgcn_readfirstlane(*flag);
  const float* in   = scrp(dout, f32, i_reg, i_off);
  const float* wt   = scrp(dout, f32, OFF_LR, w_off);
  const float* bias = scrp(dout, f32, OFF_LR, b_off);
  float* out        = scrp(dout, f32, o_reg, o_off);

  constexpr int NG = KO / KOG;
  __shared__ float tile[STG_TOT];
  const int n = blockIdx.z / NG;
  const int ko0 = (blockIdx.z % NG) * KOG;
  conv3x3_body<KO, KOG>(in, wt, bias, out, hh, ww, n, ko0, blockIdx.x * 16, blockIdx.y * 16, tile);
}

// D4: dual clf convs @64: g<5 -> enc(25ch, groups of 5); g>=5 -> enc2(9ch, groups of 3)
__global__ __launch_bounds__(256) void conv3x3_dual_k(const int* flag, void* dout) {
  const int f32 = __builtin_amdgcn_readfirstlane(*flag);
  const float* clf   = scrp(dout, f32, OFF_HR, B_CLF);
  const float* wenc  = scrp(dout, f32, OFF_LR, A_WENC);
  const float* benc  = scrp(dout, f32, OFF_LR, A_BENC);
  const float* wenc2 = scrp(dout, f32, OFF_LR, A_WENC2);
  const float* benc2 = scrp(dout, f32, OFF_LR, A_BENC2);
  float* o_ll = scrp(dout, f32, OFF_LR, A_MLRLL);
  float* o_e2 = scrp(dout, f32, OFF_LR, A_CLFE2);
  __shared__ float tile[STG_TOT];
  const int z = blockIdx.z;
  const int g = z & 7, n = z >> 3;
  const int bx = blockIdx.x * 16, by = blockIdx.y * 16;
  if (g < 5) conv3x3_body<K2L, 5>(clf, wenc, benc, o_ll, Hl, Wl, n, g * 5, bx, by, tile);
  else       conv3x3_body<K2H, 3>(clf, wenc2, benc2, o_e2, Hl, Wl, n, (g - 5) * 3, bx, by, tile);
}

// ---------------------------------------------------------------------------
// s=1 CARAFE fused residual: out = 2*feat - sum_{3x3} feat_pad * softmax?(mask)
// ---------------------------------------------------------------------------
template<typename FT, typename OT, int FINAL, int SM>
__device__ void carafe1_body(const FT* __restrict__ feat, const float* __restrict__ mask,
                             void* dout, size_t out_reg, float* outscr, int C, int CPB) {
  const int tid = threadIdx.x;
  const int tx = tid & 15, ty = tid >> 4;
  const int bx = blockIdx.x * 16, by = blockIdx.y * 16;
  const int numCG = C / CPB;
  const int n = blockIdx.z / numCG, cg = blockIdx.z % numCG;
  const int x = bx + tx, y = by + ty;
  const bool inter = (bx >= 16) && (by >= 16) && (bx + 32 <= Ww) && (by + 32 <= Hh);

  float mv[9];
  #pragma unroll
  for (int k = 0; k < 9; ++k)
    mv[k] = mask[(((size_t)n * 9 + k) * Hh + y) * Ww + x];
  if (SM) {
    float m = -1e30f;
    #pragma unroll
    for (int k = 0; k < 9; ++k) m = fmaxf(m, mv[k]);
    float s = 0.f;
    #pragma unroll
    for (int k = 0; k < 9; ++k) { mv[k] = __expf(mv[k] - m); s += mv[k]; }
    const float inv = 1.0f / s;
    #pragma unroll
    for (int k = 0; k < 9; ++k) mv[k] *= inv;
  }

  const int c0 = cg * CPB;
  if (inter) {
    for (int c = c0; c < c0 + CPB; ++c) {
      const FT* fp = feat + ((size_t)n * C + c) * HWh + (size_t)y * Ww + x;
      float center = tofloat(fp[0]);
      float s = 0.f;
      #pragma unroll
      for (int dy = -1; dy <= 1; ++dy)
        #pragma unroll
        for (int dx = -1; dx <= 1; ++dx)
          s = fmaf(tofloat(fp[dy * Ww + dx]), mv[(dy + 1) * 3 + (dx + 1)], s);
      float r = 2.f * center - s;
      const size_t li = ((size_t)n * C + c) * HWh + (size_t)y * Ww + x;
      if (FINAL) ((OT*)dout)[out_reg + li] = fromfloat<OT>(r);
      else       outscr[li] = r;
    }
  } else {
    for (int c = c0; c < c0 + CPB; ++c) {
      const FT* fp = feat + ((size_t)n * C + c) * HWh;
      float s = 0.f, center = 0.f;
      #pragma unroll
      for (int dy = -1; dy <= 1; ++dy)
        #pragma unroll
        for (int dx = -1; dx <= 1; ++dx) {
          int yy = y + dy, xx = x + dx;
          float fv = 0.f;
          if (yy >= 0 && yy < Hh && xx >= 0 && xx < Ww) fv = tofloat(fp[yy * Ww + xx]);
          if (dy == 0 && dx == 0) center = fv;
          s = fmaf(fv, mv[(dy + 1) * 3 + (dx + 1)], s);
        }
      float r = 2.f * center - s;
      const size_t li = ((size_t)n * C + c) * HWh + (size_t)y * Ww + x;
      if (FINAL) ((OT*)dout)[out_reg + li] = fromfloat<OT>(r);
      else       outscr[li] = r;
    }
  }
}

// D5: feat/mask f32 scratch, softmax fused, out scratch
__global__ __launch_bounds__(256) void carafe1_scr_k(const int* flag, void* dout,
    size_t f_reg, size_t f_off, size_t m_reg, size_t m_off, size_t o_reg, size_t o_off,
    int C, int CPB) {
  int f32 = __builtin_amdgcn_readfirstlane(*flag);
  carafe1_body<float, float, 0, 1>(scrp(dout, f32, f_reg, f_off), scrp(dout, f32, m_reg, m_off),
                                   dout, 0, scrp(dout, f32, o_reg, o_off), C, CPB);
}

// D9: feat = input hr_feat, mask raw f32 scratch (softmax fused), out final
__global__ __launch_bounds__(256) void carafe1_io_k(const int* flag, void* dout, const void* feat,
    size_t m_reg, size_t m_off, size_t out_reg, int C, int CPB) {
  int f32 = __builtin_amdgcn_readfirstlane(*flag);
  const float* m = scrp(dout, f32, m_reg, m_off);
  if (f32) carafe1_body<float, float, 1, 1>((const float*)feat, m, dout, out_reg, nullptr, C, CPB);
  else     carafe1_body<bf16, bf16, 1, 1>((const bf16*)feat, m, dout, out_reg, nullptr, C, CPB);
}

// ---------------------------------------------------------------------------
// s=2 CARAFE upsample (k=5): feat 64x64 -> out 128x128
// SM=1 softmaxes in-register; WMASK=1 additionally writes the softmaxed mask
// to final output 0 (dtype MOT) from cg==0 blocks. Interior staging fast path.
// ---------------------------------------------------------------------------
template<typename FT, typename MT, typename OT, typename MOT, int ADD, int FINAL, int SM, int WMASK>
__device__ void carafe2_body(const FT* __restrict__ feat, const MT* __restrict__ mask,
                             const float* __restrict__ addend, void* dout, size_t out_reg,
                             float* outscr, int C, int CPB) {
  __shared__ float ft[8][144];
  const int tid = threadIdx.x;
  const int tx = tid & 15, ty = tid >> 4;
  const int bx = blockIdx.x * 16, by = blockIdx.y * 16;
  const int numCG = C / CPB;
  const int n = blockIdx.z / numCG, cg = blockIdx.z % numCG;
  const int x = bx + tx, y = by + ty;
  const bool inter = (bx >= 16) && (by >= 16) && (bx + 32 <= Ww) && (by + 32 <= Hh);

  float mv[25];
  #pragma unroll
  for (int k = 0; k < 25; ++k)
    mv[k] = tofloat(mask[(((size_t)n * 25 + k) * Hh + y) * Ww + x]);
  if (SM) {
    float m = -1e30f;
    #pragma unroll
    for (int k = 0; k < 25; ++k) m = fmaxf(m, mv[k]);
    float s = 0.f;
    #pragma unroll
    for (int k = 0; k < 25; ++k) { mv[k] = __expf(mv[k] - m); s += mv[k]; }
    const float inv = 1.0f / s;
    #pragma unroll
    for (int k = 0; k < 25; ++k) mv[k] *= inv;
  }
  if (WMASK && cg == 0) {
    const size_t g = (size_t)n * 25 * HWh + (size_t)y * Ww + x;
    MOT* mo = (MOT*)dout;
    #pragma unroll
    for (int k = 0; k < 25; ++k) mo[g + (size_t)k * HWh] = fromfloat<MOT>(mv[k]);
  }

  const int fy0 = (by >> 1) - 2, fx0 = (bx >> 1) - 2;
  const int fyb = (ty >> 1) + 2, fxb = (tx >> 1) + 2;
  const int c0 = cg * CPB;

  for (int cb = 0; cb < CPB; cb += 8) {
    const int lim = (CPB - cb < 8) ? (CPB - cb) : 8;
    __syncthreads();
    if (inter) {
      for (int i = tid; i < lim * 144; i += 256) {
        int cc = i / 144, r = i % 144, fy = r / 12, fx = r % 12;
        ft[cc][r] = tofloat(feat[((size_t)n * C + c0 + cb + cc) * HWl + (fy0 + fy) * Wl + fx0 + fx]);
      }
    } else {
      for (int i = tid; i < lim * 144; i += 256) {
        int cc = i / 144, r = i % 144, fy = r / 12, fx = r % 12;
        int gy = fy0 + fy, gx = fx0 + fx;
        float v = 0.f;
        if (gy >= 0 && gy < Hl && gx >= 0 && gx < Wl)
          v = tofloat(feat[((size_t)n * C + c0 + cb + cc) * HWl + gy * Wl + gx]);
        ft[cc][r] = v;
      }
    }
    __syncthreads();
    for (int cc = 0; cc < lim; ++cc) {
      float s = 0.f;
      #pragma unroll
      for (int ki = 0; ki < 5; ++ki)
        #pragma unroll
        for (int kj = 0; kj < 5; ++kj)
          s = fmaf(ft[cc][(fyb + ki - 2) * 12 + (fxb + kj - 2)], mv[ki * 5 + kj], s);
      const size_t li = (((size_t)n * C + c0 + cb + cc) * Hh + y) * Ww + x;
      float r = ADD ? (addend[li] + s) : s;
      if (FINAL) ((OT*)dout)[out_reg + li] = fromfloat<OT>(r);
      else       outscr[li] = r;
    }
  }
}

// D7: all f32 scratch, mask raw (softmax fused), ADD
__global__ __launch_bounds__(256) void carafe2_scr_k(const int* flag, void* dout,
    size_t f_reg, size_t f_off, size_t m_reg, size_t m_off, size_t a_reg, size_t a_off,
    size_t o_reg, size_t o_off, int C, int CPB) {
  int f32 = __builtin_amdgcn_readfirstlane(*flag);
  carafe2_body<float, float, float, float, 1, 0, 1, 0>(
      scrp(dout, f32, f_reg, f_off), scrp(dout, f32, m_reg, m_off),
      scrp(dout, f32, a_reg, a_off), dout, 0, scrp(dout, f32, o_reg, o_off), C, CPB);
}

// D8: mask_hr = mask_hr_hr + carafe_s2(clf_e2, softmax(mask_lr raw)); ALSO
// writes softmax(mask_lr) to final output 0 (replaces a softmax dispatch).
__global__ __launch_bounds__(256) void carafe2_m0_k(const int* flag, void* dout,
    size_t f_reg, size_t f_off, size_t m_reg, size_t m_off, size_t a_reg, size_t a_off,
    size_t o_reg, size_t o_off, int C, int CPB) {
  int f32 = __builtin_amdgcn_readfirstlane(*flag);
  const float* f = scrp(dout, f32, f_reg, f_off);
  const float* m = scrp(dout, f32, m_reg, m_off);
  const float* a = scrp(dout, f32, a_reg, a_off);
  float* o = scrp(dout, f32, o_reg, o_off);
  if (f32) carafe2_body<float, float, float, float, 1, 0, 1, 1>(f, m, a, dout, 0, o, C, CPB);
  else     carafe2_body<float, float, float, bf16, 1, 0, 1, 1>(f, m, a, dout, 0, o, C, CPB);
}

// D10: feat = input, mask = final output 0 (already softmaxed), out = final out_lr
__global__ __launch_bounds__(256) void carafe2_io_k(const int* flag, void* dout, const void* feat,
    size_t out_reg, int C, int CPB) {
  int f32 = __builtin_amdgcn_readfirstlane(*flag);
  if (f32) carafe2_body<float, float, float, float, 0, 1, 0, 0>((const float*)feat, (const float*)dout,
      nullptr, dout, out_reg, nullptr, C, CPB);
  else     carafe2_body<bf16, bf16, bf16, bf16, 0, 1, 0, 0>((const bf16*)feat, (const bf16*)dout,
      nullptr, dout, out_reg, nullptr, C, CPB);
}

// ---------------------------------------------------------------------------
extern "C" void kernel_launch(void* const* d_in, const int* in_sizes, int n_in,
                              void* d_out, int out_size, void* d_ws, size_t ws_size,
                              hipStream_t stream) {
  const void* hr_feat = d_in[0];
  const void* lr_feat = d_in[1];
  int* flag = (int*)d_ws;  // only 4 bytes of ws used

  // D0. dtype detect
  detect_dtype<<<1, 256, 0, stream>>>(hr_feat, flag);
  // D1. weight prep -> arena A weight slots
  prep_weights<<<64, 256, 0, stream>>>(flag, d_out, d_in[2], d_in[3], d_in[4], d_in[5],
                                       d_in[6], d_in[7], d_in[8], d_in[9]);
  // D2. chf = conv1x1(hr_feat) -> A   (512 blocks, 2px/thread)
  conv1x1_k<16><<<dim3(HWh / 128, 1, Nn), 256, 0, stream>>>(flag, d_out, hr_feat, A_WHR, A_BHR, OFF_LR, A_CHF, HWh);
  // D3a. clf = conv1x1(lr_feat) -> B  (256 blocks, 2px/thread)
  conv1x1_k<8><<<dim3(HWl / 128, 2, Nn), 256, 0, stream>>>(flag, d_out, lr_feat, A_WLR, A_BLR, OFF_HR, B_CLF, HWl);
  // D3b. mask_hr_hr = conv3x3(chf, enc2) -> B  (KO=9 split x3, 768 blocks)
  conv3x3_k<K2H, 3><<<dim3(8, 8, Nn * 3), 256, 0, stream>>>(flag, d_out, OFF_LR, A_CHF, A_WENC2, A_BENC2, OFF_HR, B_MHRHR, Hh, Ww);
  // D4. {m_lr_ll, clf_e2} = conv3x3(clf, enc/enc2) -> A  (512 blocks)
  conv3x3_dual_k<<<dim3(4, 4, Nn * 8), 256, 0, stream>>>(flag, d_out);
  // D5. chf2 = 2*chf - carafe_s1(chf, softmax(mask_hr_hr)) -> B
  carafe1_scr_k<<<dim3(8, 8, Nn * (Cc / 16)), 256, 0, stream>>>(flag, d_out, OFF_LR, A_CHF, OFF_HR, B_MHRHR, OFF_HR, B_CHF2, Cc, 16);
  // D6. mask_lr_hr = conv3x3(chf2, enc) -> A (chf dead)  (KO=25 split x5, 1280 blocks)
  conv3x3_k<K2L, 5><<<dim3(8, 8, Nn * 5), 256, 0, stream>>>(flag, d_out, OFF_HR, B_CHF2, A_WENC, A_BENC, OFF_LR, A_MLRHR, Hh, Ww);
  // D7. mask_lr = mask_lr_hr + carafe_s2(m_lr_ll, softmax(mask_lr_hr)) -> B
  carafe2_scr_k<<<dim3(8, 8, Nn * 5), 256, 0, stream>>>(flag, d_out, OFF_LR, A_MLRLL, OFF_LR, A_MLRHR,
                                                        OFF_LR, A_MLRHR, OFF_HR, B_MLR, K2L, 5);
  // D8. mask_hr(raw) = mask_hr_hr + carafe_s2(clf_e2, softmax(mask_lr)) -> A
  //     + write softmax(mask_lr) -> FINAL output 0
  carafe2_m0_k<<<dim3(8, 8, Nn * 3), 256, 0, stream>>>(flag, d_out, OFF_LR, A_CLFE2,
                                                       OFF_HR, B_MLR, OFF_HR, B_MHRHR,
                                                       OFF_LR, A_MHRRAW, K2H, 3);
  // D9. hr_out = 2*hr_feat - carafe_s1(hr_feat, softmax(mask_hr)) -> FINAL out_hr
  carafe1_io_k<<<dim3(8, 8, Nn * (Ci / 32)), 256, 0, stream>>>(flag, d_out, hr_feat,
                                                               OFF_LR, A_MHRRAW, OFF_HR, Ci, 32);
  // D10 (last). lr_out = carafe_s2(lr_feat, mask_lr_out) -> FINAL out_lr (overwrites arena A)
  carafe2_io_k<<<dim3(8, 8, Nn * (Ci / 32)), 256, 0, stream>>>(flag, d_out, lr_feat, OFF_LR, Ci, 32);
}

// Round 7
// 537.091 us; speedup vs baseline: 1.2619x; 1.0598x over previous
//
#include <hip/hip_runtime.h>
#include <hip/hip_bf16.h>

typedef __hip_bfloat16 bf16;

// Problem constants
constexpr int Nn  = 4;
constexpr int Ci  = 256;
constexpr int Cc  = 64;
constexpr int Hh  = 128;
constexpr int Ww  = 128;
constexpr int HWh = Hh * Ww;
constexpr int Hl  = 64;
constexpr int Wl  = 64;
constexpr int HWl = Hl * Wl;
constexpr int K2L = 25;
constexpr int K2H = 9;

// Output element offsets (in output elements): [mask | hr_out | lr_out]
constexpr size_t OFF_MASK = 0;
constexpr size_t OFF_HR   = (size_t)Nn * K2L * HWh;            // 1,638,400
constexpr size_t OFF_LR   = OFF_HR + (size_t)Nn * Ci * HWh;    // 18,415,616

// Arena A (inside out_lr region; min capacity 8,388,608 f32 in bf16 mode)
constexpr size_t A_CHF    = 0;        // 4,194,304  [D2-D5]
constexpr size_t A_MLRHR  = 0;        // 1,638,400  [D6-D7]  (chf dead)
constexpr size_t A_MLRLL  = 4300000;  //   409,600  [D4-D7]
constexpr size_t A_CLFE2  = 4800000;  //   147,456  [D4-D8]
constexpr size_t A_MHRRAW = 5000000;  //   589,824  [D8-D9] raw mask_hr
constexpr size_t A_WHR    = 7800000;  // 16,384 weights, live D1-D6
constexpr size_t A_WLR    = 7820000;  // 16,384
constexpr size_t A_WENC   = 7840000;  // 14,400
constexpr size_t A_WENC2  = 7860000;  //  5,184
constexpr size_t A_BHR    = 7870000;  // 64
constexpr size_t A_BLR    = 7870100;  // 64
constexpr size_t A_BENC   = 7870200;  // 64
constexpr size_t A_BENC2  = 7870300;  // 64   -> top 7,870,364 < 8,388,608 OK

// Arena B (inside out_hr region)
constexpr size_t B_CLF    = 0;        // 1,048,576  [D2-D4]
constexpr size_t B_CHF2   = 1100000;  // 4,194,304  [D5-D6]
constexpr size_t B_MHRHR  = 5300000;  //   589,824  [D3-D8]  -> top 5,889,824 OK
constexpr size_t B_MLR    = 0;        // 1,638,400  [D7-D8]

__device__ __forceinline__ float tofloat(float v) { return v; }
__device__ __forceinline__ float tofloat(bf16 v) { return __bfloat162float(v); }

template<typename T> __device__ __forceinline__ T fromfloat(float v);
template<> __device__ __forceinline__ float fromfloat<float>(float v) { return v; }
template<> __device__ __forceinline__ bf16  fromfloat<bf16>(float v)  { return __float2bfloat16(v); }

// f32 scratch pointer inside an output region whose byte address depends on
// the detected output dtype (region offsets are in OUTPUT elements).
__device__ __forceinline__ float* scrp(void* d, int f32, size_t reg, size_t off) {
  float* b = f32 ? ((float*)d + reg) : (float*)((bf16*)d + reg);
  return b + off;
}

// ---------------------------------------------------------------------------
// dtype detector
// ---------------------------------------------------------------------------
__global__ void detect_dtype(const void* feat, int* flag) {
  __shared__ int s;
  if (threadIdx.x == 0) s = 0;
  __syncthreads();
  unsigned short b = ((const unsigned short*)feat)[threadIdx.x];
  float v = __uint_as_float(((unsigned int)b) << 16);
  if (!(fabsf(v) < 1000.0f)) atomicOr(&s, 1);
  __syncthreads();
  if (threadIdx.x == 0) *flag = s;
}

// ---------------------------------------------------------------------------
// Weight prep (dtype-dual)
// ---------------------------------------------------------------------------
template<typename T>
__device__ void prep_body(const T* hw, const T* hb, const T* lw, const T* lb,
                          const T* ew, const T* eb, const T* e2w, const T* e2b,
                          float* whr, float* wlr, float* wenc, float* wenc2,
                          float* bhr, float* blr, float* benc, float* benc2) {
  int tid = blockIdx.x * 256 + threadIdx.x, nt = gridDim.x * 256;
  for (int i = tid; i < Cc * Ci; i += nt) {
    int co = i / Ci, ci = i % Ci;
    whr[ci * Cc + co] = tofloat(hw[i]);
    wlr[ci * Cc + co] = tofloat(lw[i]);
  }
  for (int i = tid; i < K2L * Cc * 9; i += nt) {
    int ko = i / (Cc * 9), r = i % (Cc * 9), ci = r / 9, k = r % 9;
    wenc[(ci * K2L + ko) * 9 + k] = tofloat(ew[i]);
  }
  for (int i = tid; i < K2H * Cc * 9; i += nt) {
    int ko = i / (Cc * 9), r = i % (Cc * 9), ci = r / 9, k = r % 9;
    wenc2[(ci * K2H + ko) * 9 + k] = tofloat(e2w[i]);
  }
  if (tid < Cc)  { bhr[tid] = tofloat(hb[tid]); blr[tid] = tofloat(lb[tid]); }
  if (tid < K2L) benc[tid]  = tofloat(eb[tid]);
  if (tid < K2H) benc2[tid] = tofloat(e2b[tid]);
}

__global__ void prep_weights(const int* flag, void* dout,
                             const void* hw, const void* hb, const void* lw, const void* lb,
                             const void* ew, const void* eb, const void* e2w, const void* e2b) {
  int f32 = *flag;
  float* whr   = scrp(dout, f32, OFF_LR, A_WHR);
  float* wlr   = scrp(dout, f32, OFF_LR, A_WLR);
  float* wenc  = scrp(dout, f32, OFF_LR, A_WENC);
  float* wenc2 = scrp(dout, f32, OFF_LR, A_WENC2);
  float* bhr   = scrp(dout, f32, OFF_LR, A_BHR);
  float* blr   = scrp(dout, f32, OFF_LR, A_BLR);
  float* benc  = scrp(dout, f32, OFF_LR, A_BENC);
  float* benc2 = scrp(dout, f32, OFF_LR, A_BENC2);
  if (f32) prep_body<float>((const float*)hw, (const float*)hb, (const float*)lw, (const float*)lb,
                            (const float*)ew, (const float*)eb, (const float*)e2w, (const float*)e2b,
                            whr, wlr, wenc, wenc2, bhr, blr, benc, benc2);
  else     prep_body<bf16>((const bf16*)hw, (const bf16*)hb, (const bf16*)lw, (const bf16*)lb,
                           (const bf16*)ew, (const bf16*)eb, (const bf16*)e2w, (const bf16*)e2b,
                           whr, wlr, wenc, wenc2, bhr, blr, benc, benc2);
}

// ---------------------------------------------------------------------------
// 1x1 conv: 2 ADJACENT pixels/thread, loaded as one packed word (bf16x2 ->
// 4B, f32x2 -> 8B). unroll 8 keeps 8 loads in flight. float2 stores.
// Per-output FMA order (ci ascending) identical to before -> bit-exact.
// ---------------------------------------------------------------------------
template<typename T, int CW>
__device__ __forceinline__ void conv1x1_core(const T* __restrict__ in, const float* __restrict__ wt,
                                             const float* __restrict__ bias, float* __restrict__ out,
                                             int P, int n, int pbase, int co0) {
  const T* inp = in + (size_t)n * Ci * P + pbase;
  float acc0[CW], acc1[CW];
  #pragma unroll
  for (int c = 0; c < CW; ++c) { float b = bias[co0 + c]; acc0[c] = b; acc1[c] = b; }

  #pragma unroll 8
  for (int ci = 0; ci < Ci; ++ci) {
    float v0, v1;
    if (sizeof(T) == 2) {
      unsigned u = *reinterpret_cast<const unsigned*>(inp + (size_t)ci * P);
      v0 = __uint_as_float(u << 16);           // low half-word = pixel pbase
      v1 = __uint_as_float(u & 0xffff0000u);   // high half-word = pixel pbase+1
    } else {
      float2 f = *reinterpret_cast<const float2*>(inp + (size_t)ci * P);
      v0 = f.x; v1 = f.y;
    }
    const float* wr = wt + ci * Cc + co0;
    #pragma unroll
    for (int c = 0; c < CW; ++c) {
      float wv = wr[c];
      acc0[c] = fmaf(v0, wv, acc0[c]);
      acc1[c] = fmaf(v1, wv, acc1[c]);
    }
  }
  float* op = out + (size_t)n * Cc * P + pbase;
  #pragma unroll
  for (int c = 0; c < CW; ++c)
    *reinterpret_cast<float2*>(op + (size_t)(co0 + c) * P) = make_float2(acc0[c], acc1[c]);
}

template<int CW>
__global__ __launch_bounds__(256) void conv1x1_k(const int* flag, void* dout, const void* in,
                                                 size_t w_off, size_t b_off,
                                                 size_t o_reg, size_t o_off, int P) {
  int f32 = __builtin_amdgcn_readfirstlane(*flag);
  const float* wt   = scrp(dout, f32, OFF_LR, w_off);
  const float* bias = scrp(dout, f32, OFF_LR, b_off);
  float* out        = scrp(dout, f32, o_reg, o_off);
  const int tid = threadIdx.x;
  const int n = blockIdx.z;
  const int pbase = (blockIdx.x * 64 + (tid & 63)) * 2;   // 128 px per block
  const int co0 = __builtin_amdgcn_readfirstlane(blockIdx.y * 4 * CW + (tid >> 6) * CW);
  if (f32) conv1x1_core<float, CW>((const float*)in, wt, bias, out, P, n, pbase, co0);
  else     conv1x1_core<bf16, CW>((const bf16*)in, wt, bias, out, P, n, pbase, co0);
}

// ---------------------------------------------------------------------------
// 3x3 conv body, pad=1 (f32 scratch in/out); computes KOG of KO channels.
// Register-staged prefetch: next chunk's global loads are issued BEFORE the
// current chunk's compute, hiding HBM/L2 latency under the FMA block.
// ---------------------------------------------------------------------------
constexpr int STG_TOT = 16 * 324;        // 5184 floats per chunk
constexpr int NSTG    = 21;              // ceil(5184/256) regs per thread

template<int KO, int KOG>
__device__ __forceinline__ void conv3x3_body(const float* __restrict__ in,
                                             const float* __restrict__ wt,
                                             const float* __restrict__ bias,
                                             float* __restrict__ out,
                                             int hh, int ww, int n, int ko0,
                                             int bx, int by, float* tile) {
  const int tid = threadIdx.x;
  const int tx = tid & 15, ty = tid >> 4;
  const bool inter = (bx >= 16) && (by >= 16) && (bx + 32 <= ww) && (by + 32 <= hh);

  float acc[KOG];
  #pragma unroll
  for (int ko = 0; ko < KOG; ++ko) acc[ko] = bias[ko0 + ko];

  float rg[NSTG];
  // prologue: load chunk cc=0 into registers
  #pragma unroll
  for (int j = 0; j < NSTG; ++j) {
    int i = tid + j * 256;
    if (i < STG_TOT) {
      int ci = i / 324, r = i % 324, yy = r / 18, xx = r % 18;
      int gy = by + yy - 1, gx = bx + xx - 1;
      float v = 0.f;
      if (inter || (gy >= 0 && gy < hh && gx >= 0 && gx < ww))
        v = in[(((size_t)n * Cc + ci) * hh + gy) * ww + gx];
      rg[j] = v;
    }
  }

  for (int cc = 0; cc < Cc; cc += 16) {
    __syncthreads();
    #pragma unroll
    for (int j = 0; j < NSTG; ++j) {
      int i = tid + j * 256;
      if (i < STG_TOT) tile[i] = rg[j];
    }
    __syncthreads();
    if (cc + 16 < Cc) {
      // issue next chunk's loads now; they complete under the compute below
      #pragma unroll
      for (int j = 0; j < NSTG; ++j) {
        int i = tid + j * 256;
        if (i < STG_TOT) {
          int ci = i / 324, r = i % 324, yy = r / 18, xx = r % 18;
          int gy = by + yy - 1, gx = bx + xx - 1;
          float v = 0.f;
          if (inter || (gy >= 0 && gy < hh && gx >= 0 && gx < ww))
            v = in[(((size_t)n * Cc + cc + 16 + ci) * hh + gy) * ww + gx];
          rg[j] = v;
        }
      }
    }
    for (int ci = 0; ci < 16; ++ci) {
      float nb[9];
      #pragma unroll
      for (int dy = 0; dy < 3; ++dy)
        #pragma unroll
        for (int dx = 0; dx < 3; ++dx)
          nb[dy * 3 + dx] = tile[ci * 324 + (ty + dy) * 18 + tx + dx];
      const float* wr = wt + ((size_t)(cc + ci) * KO + ko0) * 9;
      #pragma unroll
      for (int ko = 0; ko < KOG; ++ko)
        #pragma unroll
        for (int k = 0; k < 9; ++k)
          acc[ko] = fmaf(wr[ko * 9 + k], nb[k], acc[ko]);
    }
  }
  const size_t ob = (((size_t)n * KO + ko0) * hh + by + ty) * ww + bx + tx;
  #pragma unroll
  for (int ko = 0; ko < KOG; ++ko) out[ob + (size_t)ko * hh * ww] = acc[ko];
}

template<int KO, int KOG>
__global__ __launch_bounds__(256) void conv3x3_k(const int* flag, void* dout,
                                                 size_t i_reg, size_t i_off,
                                                 size_t w_off, size_t b_off,
                                                 size_t o_reg, size_t o_off, int hh, int ww) {
  const int f32 = __builtin_amdgcn_readfirstlane(*flag);
  const float* in   = scrp(dout, f32, i_reg, i_off);
  const float* wt   = scrp(dout, f32, OFF_LR, w_off);
  const float* bias = scrp(dout, f32, OFF_LR, b_off);
  float* out        = scrp(dout, f32, o_reg, o_off);

  constexpr int NG = KO / KOG;
  __shared__ float tile[STG_TOT];
  const int n = blockIdx.z / NG;
  const int ko0 = (blockIdx.z % NG) * KOG;
  conv3x3_body<KO, KOG>(in, wt, bias, out, hh, ww, n, ko0, blockIdx.x * 16, blockIdx.y * 16, tile);
}

// D4: dual clf convs @64: g<5 -> enc(25ch, groups of 5); g>=5 -> enc2(9ch, groups of 3)
__global__ __launch_bounds__(256) void conv3x3_dual_k(const int* flag, void* dout) {
  const int f32 = __builtin_amdgcn_readfirstlane(*flag);
  const float* clf   = scrp(dout, f32, OFF_HR, B_CLF);
  const float* wenc  = scrp(dout, f32, OFF_LR, A_WENC);
  const float* benc  = scrp(dout, f32, OFF_LR, A_BENC);
  const float* wenc2 = scrp(dout, f32, OFF_LR, A_WENC2);
  const float* benc2 = scrp(dout, f32, OFF_LR, A_BENC2);
  float* o_ll = scrp(dout, f32, OFF_LR, A_MLRLL);
  float* o_e2 = scrp(dout, f32, OFF_LR, A_CLFE2);
  __shared__ float tile[STG_TOT];
  const int z = blockIdx.z;
  const int g = z & 7, n = z >> 3;
  const int bx = blockIdx.x * 16, by = blockIdx.y * 16;
  if (g < 5) conv3x3_body<K2L, 5>(clf, wenc, benc, o_ll, Hl, Wl, n, g * 5, bx, by, tile);
  else       conv3x3_body<K2H, 3>(clf, wenc2, benc2, o_e2, Hl, Wl, n, (g - 5) * 3, bx, by, tile);
}

// ---------------------------------------------------------------------------
// s=1 CARAFE fused residual: out = 2*feat - sum_{3x3} feat_pad * softmax?(mask)
// ---------------------------------------------------------------------------
template<typename FT, typename OT, int FINAL, int SM>
__device__ void carafe1_body(const FT* __restrict__ feat, const float* __restrict__ mask,
                             void* dout, size_t out_reg, float* outscr, int C, int CPB) {
  const int tid = threadIdx.x;
  const int tx = tid & 15, ty = tid >> 4;
  const int bx = blockIdx.x * 16, by = blockIdx.y * 16;
  const int numCG = C / CPB;
  const int n = blockIdx.z / numCG, cg = blockIdx.z % numCG;
  const int x = bx + tx, y = by + ty;
  const bool inter = (bx >= 16) && (by >= 16) && (bx + 32 <= Ww) && (by + 32 <= Hh);

  float mv[9];
  #pragma unroll
  for (int k = 0; k < 9; ++k)
    mv[k] = mask[(((size_t)n * 9 + k) * Hh + y) * Ww + x];
  if (SM) {
    float m = -1e30f;
    #pragma unroll
    for (int k = 0; k < 9; ++k) m = fmaxf(m, mv[k]);
    float s = 0.f;
    #pragma unroll
    for (int k = 0; k < 9; ++k) { mv[k] = __expf(mv[k] - m); s += mv[k]; }
    const float inv = 1.0f / s;
    #pragma unroll
    for (int k = 0; k < 9; ++k) mv[k] *= inv;
  }

  const int c0 = cg * CPB;
  if (inter) {
    for (int c = c0; c < c0 + CPB; ++c) {
      const FT* fp = feat + ((size_t)n * C + c) * HWh + (size_t)y * Ww + x;
      float center = tofloat(fp[0]);
      float s = 0.f;
      #pragma unroll
      for (int dy = -1; dy <= 1; ++dy)
        #pragma unroll
        for (int dx = -1; dx <= 1; ++dx)
          s = fmaf(tofloat(fp[dy * Ww + dx]), mv[(dy + 1) * 3 + (dx + 1)], s);
      float r = 2.f * center - s;
      const size_t li = ((size_t)n * C + c) * HWh + (size_t)y * Ww + x;
      if (FINAL) ((OT*)dout)[out_reg + li] = fromfloat<OT>(r);
      else       outscr[li] = r;
    }
  } else {
    for (int c = c0; c < c0 + CPB; ++c) {
      const FT* fp = feat + ((size_t)n * C + c) * HWh;
      float s = 0.f, center = 0.f;
      #pragma unroll
      for (int dy = -1; dy <= 1; ++dy)
        #pragma unroll
        for (int dx = -1; dx <= 1; ++dx) {
          int yy = y + dy, xx = x + dx;
          float fv = 0.f;
          if (yy >= 0 && yy < Hh && xx >= 0 && xx < Ww) fv = tofloat(fp[yy * Ww + xx]);
          if (dy == 0 && dx == 0) center = fv;
          s = fmaf(fv, mv[(dy + 1) * 3 + (dx + 1)], s);
        }
      float r = 2.f * center - s;
      const size_t li = ((size_t)n * C + c) * HWh + (size_t)y * Ww + x;
      if (FINAL) ((OT*)dout)[out_reg + li] = fromfloat<OT>(r);
      else       outscr[li] = r;
    }
  }
}

// D5: feat/mask f32 scratch, softmax fused, out scratch
__global__ __launch_bounds__(256) void carafe1_scr_k(const int* flag, void* dout,
    size_t f_reg, size_t f_off, size_t m_reg, size_t m_off, size_t o_reg, size_t o_off,
    int C, int CPB) {
  int f32 = __builtin_amdgcn_readfirstlane(*flag);
  carafe1_body<float, float, 0, 1>(scrp(dout, f32, f_reg, f_off), scrp(dout, f32, m_reg, m_off),
                                   dout, 0, scrp(dout, f32, o_reg, o_off), C, CPB);
}

// D9: feat = input hr_feat, mask raw f32 scratch (softmax fused), out final
__global__ __launch_bounds__(256) void carafe1_io_k(const int* flag, void* dout, const void* feat,
    size_t m_reg, size_t m_off, size_t out_reg, int C, int CPB) {
  int f32 = __builtin_amdgcn_readfirstlane(*flag);
  const float* m = scrp(dout, f32, m_reg, m_off);
  if (f32) carafe1_body<float, float, 1, 1>((const float*)feat, m, dout, out_reg, nullptr, C, CPB);
  else     carafe1_body<bf16, bf16, 1, 1>((const bf16*)feat, m, dout, out_reg, nullptr, C, CPB);
}

// ---------------------------------------------------------------------------
// s=2 CARAFE upsample (k=5): feat 64x64 -> out 128x128
// SM=1 softmaxes in-register; WMASK=1 additionally writes the softmaxed mask
// to final output 0 (dtype MOT) from cg==0 blocks. Interior staging fast path.
// ---------------------------------------------------------------------------
template<typename FT, typename MT, typename OT, typename MOT, int ADD, int FINAL, int SM, int WMASK>
__device__ void carafe2_body(const FT* __restrict__ feat, const MT* __restrict__ mask,
                             const float* __restrict__ addend, void* dout, size_t out_reg,
                             float* outscr, int C, int CPB) {
  __shared__ float ft[8][144];
  const int tid = threadIdx.x;
  const int tx = tid & 15, ty = tid >> 4;
  const int bx = blockIdx.x * 16, by = blockIdx.y * 16;
  const int numCG = C / CPB;
  const int n = blockIdx.z / numCG, cg = blockIdx.z % numCG;
  const int x = bx + tx, y = by + ty;
  const bool inter = (bx >= 16) && (by >= 16) && (bx + 32 <= Ww) && (by + 32 <= Hh);

  float mv[25];
  #pragma unroll
  for (int k = 0; k < 25; ++k)
    mv[k] = tofloat(mask[(((size_t)n * 25 + k) * Hh + y) * Ww + x]);
  if (SM) {
    float m = -1e30f;
    #pragma unroll
    for (int k = 0; k < 25; ++k) m = fmaxf(m, mv[k]);
    float s = 0.f;
    #pragma unroll
    for (int k = 0; k < 25; ++k) { mv[k] = __expf(mv[k] - m); s += mv[k]; }
    const float inv = 1.0f / s;
    #pragma unroll
    for (int k = 0; k < 25; ++k) mv[k] *= inv;
  }
  if (WMASK && cg == 0) {
    const size_t g = (size_t)n * 25 * HWh + (size_t)y * Ww + x;
    MOT* mo = (MOT*)dout;
    #pragma unroll
    for (int k = 0; k < 25; ++k) mo[g + (size_t)k * HWh] = fromfloat<MOT>(mv[k]);
  }

  const int fy0 = (by >> 1) - 2, fx0 = (bx >> 1) - 2;
  const int fyb = (ty >> 1) + 2, fxb = (tx >> 1) + 2;
  const int c0 = cg * CPB;

  for (int cb = 0; cb < CPB; cb += 8) {
    const int lim = (CPB - cb < 8) ? (CPB - cb) : 8;
    __syncthreads();
    if (inter) {
      for (int i = tid; i < lim * 144; i += 256) {
        int cc = i / 144, r = i % 144, fy = r / 12, fx = r % 12;
        ft[cc][r] = tofloat(feat[((size_t)n * C + c0 + cb + cc) * HWl + (fy0 + fy) * Wl + fx0 + fx]);
      }
    } else {
      for (int i = tid; i < lim * 144; i += 256) {
        int cc = i / 144, r = i % 144, fy = r / 12, fx = r % 12;
        int gy = fy0 + fy, gx = fx0 + fx;
        float v = 0.f;
        if (gy >= 0 && gy < Hl && gx >= 0 && gx < Wl)
          v = tofloat(feat[((size_t)n * C + c0 + cb + cc) * HWl + gy * Wl + gx]);
        ft[cc][r] = v;
      }
    }
    __syncthreads();
    for (int cc = 0; cc < lim; ++cc) {
      float s = 0.f;
      #pragma unroll
      for (int ki = 0; ki < 5; ++ki)
        #pragma unroll
        for (int kj = 0; kj < 5; ++kj)
          s = fmaf(ft[cc][(fyb + ki - 2) * 12 + (fxb + kj - 2)], mv[ki * 5 + kj], s);
      const size_t li = (((size_t)n * C + c0 + cb + cc) * Hh + y) * Ww + x;
      float r = ADD ? (addend[li] + s) : s;
      if (FINAL) ((OT*)dout)[out_reg + li] = fromfloat<OT>(r);
      else       outscr[li] = r;
    }
  }
}

// D7: all f32 scratch, mask raw (softmax fused), ADD
__global__ __launch_bounds__(256) void carafe2_scr_k(const int* flag, void* dout,
    size_t f_reg, size_t f_off, size_t m_reg, size_t m_off, size_t a_reg, size_t a_off,
    size_t o_reg, size_t o_off, int C, int CPB) {
  int f32 = __builtin_amdgcn_readfirstlane(*flag);
  carafe2_body<float, float, float, float, 1, 0, 1, 0>(
      scrp(dout, f32, f_reg, f_off), scrp(dout, f32, m_reg, m_off),
      scrp(dout, f32, a_reg, a_off), dout, 0, scrp(dout, f32, o_reg, o_off), C, CPB);
}

// D8: mask_hr = mask_hr_hr + carafe_s2(clf_e2, softmax(mask_lr raw)); ALSO
// writes softmax(mask_lr) to final output 0 (replaces a softmax dispatch).
__global__ __launch_bounds__(256) void carafe2_m0_k(const int* flag, void* dout,
    size_t f_reg, size_t f_off, size_t m_reg, size_t m_off, size_t a_reg, size_t a_off,
    size_t o_reg, size_t o_off, int C, int CPB) {
  int f32 = __builtin_amdgcn_readfirstlane(*flag);
  const float* f = scrp(dout, f32, f_reg, f_off);
  const float* m = scrp(dout, f32, m_reg, m_off);
  const float* a = scrp(dout, f32, a_reg, a_off);
  float* o = scrp(dout, f32, o_reg, o_off);
  if (f32) carafe2_body<float, float, float, float, 1, 0, 1, 1>(f, m, a, dout, 0, o, C, CPB);
  else     carafe2_body<float, float, float, bf16, 1, 0, 1, 1>(f, m, a, dout, 0, o, C, CPB);
}

// D10: feat = input, mask = final output 0 (already softmaxed), out = final out_lr
__global__ __launch_bounds__(256) void carafe2_io_k(const int* flag, void* dout, const void* feat,
    size_t out_reg, int C, int CPB) {
  int f32 = __builtin_amdgcn_readfirstlane(*flag);
  if (f32) carafe2_body<float, float, float, float, 0, 1, 0, 0>((const float*)feat, (const float*)dout,
      nullptr, dout, out_reg, nullptr, C, CPB);
  else     carafe2_body<bf16, bf16, bf16, bf16, 0, 1, 0, 0>((const bf16*)feat, (const bf16*)dout,
      nullptr, dout, out_reg, nullptr, C, CPB);
}

// ---------------------------------------------------------------------------
extern "C" void kernel_launch(void* const* d_in, const int* in_sizes, int n_in,
                              void* d_out, int out_size, void* d_ws, size_t ws_size,
                              hipStream_t stream) {
  const void* hr_feat = d_in[0];
  const void* lr_feat = d_in[1];
  int* flag = (int*)d_ws;  // only 4 bytes of ws used

  // D0. dtype detect
  detect_dtype<<<1, 256, 0, stream>>>(hr_feat, flag);
  // D1. weight prep -> arena A weight slots
  prep_weights<<<64, 256, 0, stream>>>(flag, d_out, d_in[2], d_in[3], d_in[4], d_in[5],
                                       d_in[6], d_in[7], d_in[8], d_in[9]);
  // D2. chf = conv1x1(hr_feat) -> A   (CW=8, 2-adjacent-px packed, 1024 blocks)
  conv1x1_k<8><<<dim3(HWh / 128, 2, Nn), 256, 0, stream>>>(flag, d_out, hr_feat, A_WHR, A_BHR, OFF_LR, A_CHF, HWh);
  // D3a. clf = conv1x1(lr_feat) -> B  (CW=4, 512 blocks)
  conv1x1_k<4><<<dim3(HWl / 128, 4, Nn), 256, 0, stream>>>(flag, d_out, lr_feat, A_WLR, A_BLR, OFF_HR, B_CLF, HWl);
  // D3b. mask_hr_hr = conv3x3(chf, enc2) -> B  (KO=9 split x3, 768 blocks)
  conv3x3_k<K2H, 3><<<dim3(8, 8, Nn * 3), 256, 0, stream>>>(flag, d_out, OFF_LR, A_CHF, A_WENC2, A_BENC2, OFF_HR, B_MHRHR, Hh, Ww);
  // D4. {m_lr_ll, clf_e2} = conv3x3(clf, enc/enc2) -> A  (512 blocks)
  conv3x3_dual_k<<<dim3(4, 4, Nn * 8), 256, 0, stream>>>(flag, d_out);
  // D5. chf2 = 2*chf - carafe_s1(chf, softmax(mask_hr_hr)) -> B
  carafe1_scr_k<<<dim3(8, 8, Nn * (Cc / 16)), 256, 0, stream>>>(flag, d_out, OFF_LR, A_CHF, OFF_HR, B_MHRHR, OFF_HR, B_CHF2, Cc, 16);
  // D6. mask_lr_hr = conv3x3(chf2, enc) -> A (chf dead)  (KO=25 split x5, 1280 blocks)
  conv3x3_k<K2L, 5><<<dim3(8, 8, Nn * 5), 256, 0, stream>>>(flag, d_out, OFF_HR, B_CHF2, A_WENC, A_BENC, OFF_LR, A_MLRHR, Hh, Ww);
  // D7. mask_lr = mask_lr_hr + carafe_s2(m_lr_ll, softmax(mask_lr_hr)) -> B
  carafe2_scr_k<<<dim3(8, 8, Nn * 5), 256, 0, stream>>>(flag, d_out, OFF_LR, A_MLRLL, OFF_LR, A_MLRHR,
                                                        OFF_LR, A_MLRHR, OFF_HR, B_MLR, K2L, 5);
  // D8. mask_hr(raw) = mask_hr_hr + carafe_s2(clf_e2, softmax(mask_lr)) -> A
  //     + write softmax(mask_lr) -> FINAL output 0
  carafe2_m0_k<<<dim3(8, 8, Nn * 3), 256, 0, stream>>>(flag, d_out, OFF_LR, A_CLFE2,
                                                       OFF_HR, B_MLR, OFF_HR, B_MHRHR,
                                                       OFF_LR, A_MHRRAW, K2H, 3);
  // D9. hr_out = 2*hr_feat - carafe_s1(hr_feat, softmax(mask_hr)) -> FINAL out_hr
  carafe1_io_k<<<dim3(8, 8, Nn * (Ci / 32)), 256, 0, stream>>>(flag, d_out, hr_feat,
                                                               OFF_LR, A_MHRRAW, OFF_HR, Ci, 32);
  // D10 (last). lr_out = carafe_s2(lr_feat, mask_lr_out) -> FINAL out_lr (overwrites arena A)
  carafe2_io_k<<<dim3(8, 8, Nn * (Ci / 32)), 256, 0, stream>>>(flag, d_out, lr_feat, OFF_LR, Ci, 32);
}